// Round 5
// baseline (514.783 us; speedup 1.0000x reference)
//
#include <hip/hip_runtime.h>
#include <hip/hip_bf16.h>
#include <math.h>

typedef __hip_bfloat16 bf16_t;
typedef __attribute__((ext_vector_type(8))) short short8;
typedef __attribute__((ext_vector_type(4))) float floatx4;

#define T_SEQ 2048
#define NB    4
#define NH    16
#define HD    64
#define C_DIM 1024
#define M_ROWS (NB * T_SEQ)   // 8192

// Q pre-scale: (1/sqrt(64)) * log2(e) so scores are in log2 units and
// P = exp2(s) directly (unnormalized softmax; shift cancels in O = sum(Pv)/sum(P)).
#define Q_SCALE 0.18033688011f

// ---------------------------------------------------------------- helpers
__device__ __forceinline__ void load_lds16(const bf16_t* g, bf16_t* l) {
    __builtin_amdgcn_global_load_lds(
        (const __attribute__((address_space(1))) void*)g,
        (__attribute__((address_space(3))) void*)l,
        16, 0, 0);
}

__device__ __forceinline__ floatx4 mfma16(short8 a, short8 b, floatx4 c) {
    return __builtin_amdgcn_mfma_f32_16x16x32_bf16(a, b, c, 0, 0, 0);
}

// ---------------------------------------------------------------- converts
__global__ void convert_x_kernel(const float* __restrict__ x, bf16_t* __restrict__ xb) {
    int i = blockIdx.x * 256 + threadIdx.x;   // one float4 per thread
    float4 v = reinterpret_cast<const float4*>(x)[i];
    union { bf16_t h[4]; short4 s4; } u;
    u.h[0] = __float2bfloat16(v.x);
    u.h[1] = __float2bfloat16(v.y);
    u.h[2] = __float2bfloat16(v.z);
    u.h[3] = __float2bfloat16(v.w);
    reinterpret_cast<short4*>(xb)[i] = u.s4;
}

// W [K,N] fp32 -> Wt [N,K] bf16, LDS-tiled transpose. block (32,8), grid (32,32,4)
__global__ void transpose_cvt_kernel(const float* __restrict__ W0, const float* __restrict__ W1,
                                     const float* __restrict__ W2, const float* __restrict__ W3,
                                     bf16_t* __restrict__ O0, bf16_t* __restrict__ O1,
                                     bf16_t* __restrict__ O2, bf16_t* __restrict__ O3) {
    const float* W = (blockIdx.z == 0) ? W0 : (blockIdx.z == 1) ? W1 : (blockIdx.z == 2) ? W2 : W3;
    bf16_t*      O = (blockIdx.z == 0) ? O0 : (blockIdx.z == 1) ? O1 : (blockIdx.z == 2) ? O2 : O3;
    __shared__ float tile[32][33];
    int bx = blockIdx.x * 32, by = blockIdx.y * 32;
    int tx = threadIdx.x, ty = threadIdx.y;
#pragma unroll
    for (int j = 0; j < 32; j += 8)
        tile[ty + j][tx] = W[(size_t)(by + ty + j) * C_DIM + bx + tx];
    __syncthreads();
#pragma unroll
    for (int j = 0; j < 32; j += 8)
        O[(size_t)(bx + ty + j) * C_DIM + by + tx] = __float2bfloat16(tile[tx][ty + j]);
}

// ---------------------------------------------------------------- GEMM mainloop
// C[128,128] += A[128,K] * Bt[128,K]^T  (both row-major, K-contiguous), BK=64.
// LDS layout XOR-swizzled: 16B piece p of row r lives at piece slot (p ^ (r&7)).
__device__ __forceinline__ void gemm_mainloop(const bf16_t* __restrict__ Ablk,
                                              const bf16_t* __restrict__ Bblk,
                                              bf16_t* As, bf16_t* Bs,
                                              floatx4 acc[4][4], int wave, int lane) {
    int lr = lane & 15, lq = lane >> 4;
    int wr = (wave >> 1) * 64, wc = (wave & 1) * 64;
    for (int kt = 0; kt < C_DIM; kt += 64) {
#pragma unroll
        for (int j = 0; j < 4; ++j) {
            int chunk = j * 256 + wave * 64 + lane;       // 0..1023, wave-contiguous
            int r = chunk >> 3, ps = chunk & 7;
            int c = ((ps ^ (r & 7)) * 8);                 // swizzled source column
            load_lds16(Ablk + (size_t)r * C_DIM + kt + c, As + chunk * 8);
            load_lds16(Bblk + (size_t)r * C_DIM + kt + c, Bs + chunk * 8);
        }
        __syncthreads();
#pragma unroll
        for (int kk = 0; kk < 2; ++kk) {
            short8 af[4], bfr[4];
            int psw = ((kk * 4 + lq) ^ (lr & 7)) * 8;     // swizzled piece offset
#pragma unroll
            for (int m = 0; m < 4; ++m)
                af[m] = *reinterpret_cast<const short8*>(As + (wr + m * 16 + lr) * 64 + psw);
#pragma unroll
            for (int n = 0; n < 4; ++n)
                bfr[n] = *reinterpret_cast<const short8*>(Bs + (wc + n * 16 + lr) * 64 + psw);
#pragma unroll
            for (int m = 0; m < 4; ++m)
#pragma unroll
                for (int n = 0; n < 4; ++n)
                    acc[m][n] = mfma16(af[m], bfr[n], acc[m][n]);
        }
        __syncthreads();
    }
}

// ---------------------------------------------------------------- QKV GEMM
// grid (8, 64, 3): z=0 Q (scaled Q_SCALE), z=1 K, z=2 V (transposed store)
__global__ __launch_bounds__(256, 2) void gemm_qkv_kernel(
    const bf16_t* __restrict__ xb,
    const bf16_t* __restrict__ WqT, const bf16_t* __restrict__ WkT, const bf16_t* __restrict__ WvT,
    const float* __restrict__ bq, const float* __restrict__ bk, const float* __restrict__ bv,
    bf16_t* __restrict__ Q, bf16_t* __restrict__ K, bf16_t* __restrict__ Vt) {
    __shared__ bf16_t As[128 * 64];
    __shared__ bf16_t Bs[128 * 64];
    int tid = threadIdx.x, wave = tid >> 6, lane = tid & 63;
    int row0 = blockIdx.y * 128, col0 = blockIdx.x * 128;
    int wsel = blockIdx.z;
    const bf16_t* Wt  = (wsel == 0) ? WqT : (wsel == 1) ? WkT : WvT;
    const float* bias = (wsel == 0) ? bq : (wsel == 1) ? bk : bv;

    floatx4 acc[4][4] = {};
    gemm_mainloop(xb + (size_t)row0 * C_DIM, Wt + (size_t)col0 * C_DIM, As, Bs, acc, wave, lane);

    int lr = lane & 15, lq = lane >> 4;
    int wr = (wave >> 1) * 64, wc = (wave & 1) * 64;
    float scale = (wsel == 0) ? Q_SCALE : 1.0f;
    bf16_t* outp = (wsel == 0) ? Q : (wsel == 1) ? K : Vt;
    bool vtrans = (wsel == 2);
#pragma unroll
    for (int nt = 0; nt < 4; ++nt) {
        int col = col0 + wc + nt * 16 + lr;
        float bvv = bias[col];
        int h = col >> 6, d = col & 63;
#pragma unroll
        for (int m = 0; m < 4; ++m) {
#pragma unroll
            for (int r = 0; r < 4; ++r) {
                int rowg = row0 + wr + m * 16 + lq * 4 + r;
                int b = rowg >> 11, t = rowg & (T_SEQ - 1);
                float val = (acc[m][nt][r] + bvv) * scale;
                size_t idx = vtrans
                    ? ((size_t)((b * NH + h) * HD + d)) * T_SEQ + t
                    : ((size_t)((b * NH + h) * T_SEQ + t)) * HD + d;
                outp[idx] = __float2bfloat16(val);
            }
        }
    }
}

// ---------------------------------------------------------------- attention
// Barrier-free flash attention. grid (16, 64): one q-tile per block.
// K/V fragments loaded DIRECTLY from global (L2/LLC-resident: K+V = 32 MB) —
// no LDS staging, no double buffer, no __syncthreads at all. Only LDS use is
// the wave-private P C->A layout round trip (16 KB).
// qt = (x + (y>>2)) & 15 rotates q-tile length across the blocks a CU
// receives under round-robin placement -> per-CU work spread ~±18%.
// Unnormalized softmax: P = exp2(s), per-lane l partials, epilogue reduce.
__global__ __launch_bounds__(256, 4) void attn_kernel(
    const bf16_t* __restrict__ Q, const bf16_t* __restrict__ K,
    const bf16_t* __restrict__ Vt, bf16_t* __restrict__ ctx) {
    __shared__ __align__(16) bf16_t Ps[128 * 64];     // P tile [q][k], swizzled
    int tid = threadIdx.x, wave = tid >> 6, lane = tid & 63;
    int lr = lane & 15, lq = lane >> 4;
    int bh = blockIdx.y;
    int b = bh >> 4, h = bh & 15;
    int qt = (int)((blockIdx.x + (blockIdx.y >> 2)) & 15);
    int q0 = qt * 128;
    int ktiles = 2 * qt + 2;

    const bf16_t* Qbase = Q  + ((size_t)bh * T_SEQ + q0) * HD;
    const bf16_t* Kbase = K  + (size_t)bh * T_SEQ * HD;
    const bf16_t* Vbase = Vt + (size_t)bh * HD * T_SEQ;

    // Q fragments in registers: rows [wave*32, wave*32+32)
    short8 qf[2][2];
#pragma unroll
    for (int m = 0; m < 2; ++m)
#pragma unroll
        for (int kk = 0; kk < 2; ++kk)
            qf[m][kk] = *reinterpret_cast<const short8*>(
                Qbase + (size_t)(wave * 32 + m * 16 + lr) * HD + kk * 32 + lq * 8);

    floatx4 o[2][4] = {};
    float lpart[2][4] = {};

    for (int it = 0; it < ktiles; ++it) {
        int kt0 = it * 64;

        // K/V fragments straight from global (b128 loads, L2/LLC hits)
        short8 kf[4][2], vf[4][2];
#pragma unroll
        for (int n = 0; n < 4; ++n)
#pragma unroll
            for (int kk = 0; kk < 2; ++kk)
                kf[n][kk] = *reinterpret_cast<const short8*>(
                    Kbase + (size_t)(kt0 + n * 16 + lr) * HD + kk * 32 + lq * 8);
#pragma unroll
        for (int dt = 0; dt < 4; ++dt)
#pragma unroll
            for (int kk = 0; kk < 2; ++kk)
                vf[dt][kk] = *reinterpret_cast<const short8*>(
                    Vbase + (size_t)(dt * 16 + lr) * T_SEQ + kt0 + kk * 32 + lq * 8);

        // S = Q K^T (log2 units)
        floatx4 s[2][4] = {};
#pragma unroll
        for (int kk = 0; kk < 2; ++kk)
#pragma unroll
            for (int m = 0; m < 2; ++m)
#pragma unroll
                for (int n = 0; n < 4; ++n)
                    s[m][n] = mfma16(qf[m][kk], kf[n][kk], s[m][n]);

        // causal mask only on the last two tiles (block-uniform branch)
        if (it >= ktiles - 2) {
#pragma unroll
            for (int m = 0; m < 2; ++m)
#pragma unroll
                for (int r = 0; r < 4; ++r) {
                    int rowg = q0 + wave * 32 + m * 16 + lq * 4 + r;
#pragma unroll
                    for (int n = 0; n < 4; ++n) {
                        int colg = kt0 + n * 16 + lr;
                        if (colg > rowg) s[m][n][r] = -1e30f;
                    }
                }
        }

        // P = exp2(s); accumulate per-lane l partials (no cross-lane ops)
#pragma unroll
        for (int m = 0; m < 2; ++m)
#pragma unroll
            for (int n = 0; n < 4; ++n)
#pragma unroll
                for (int r = 0; r < 4; ++r)
                    s[m][n][r] = exp2f(s[m][n][r]);
#pragma unroll
        for (int m = 0; m < 2; ++m)
#pragma unroll
            for (int r = 0; r < 4; ++r)
                lpart[m][r] += (s[m][0][r] + s[m][1][r]) + (s[m][2][r] + s[m][3][r]);

        // dump P to LDS (C-layout -> A-layout; rows are wave-private,
        // lgkmcnt orders wave-local write->read, no barrier needed)
#pragma unroll
        for (int m = 0; m < 2; ++m)
#pragma unroll
            for (int n = 0; n < 4; ++n)
#pragma unroll
                for (int r = 0; r < 4; ++r) {
                    int prow = wave * 32 + m * 16 + lq * 4 + r;
                    int piece = n * 2 + (lr >> 3);
                    Ps[prow * 64 + ((piece ^ (prow & 7)) * 8) + (lr & 7)] =
                        __float2bfloat16(s[m][n][r]);
                }

        // O += P V
        short8 pf[2][2];
#pragma unroll
        for (int m = 0; m < 2; ++m)
#pragma unroll
            for (int kk = 0; kk < 2; ++kk) {
                int prow = wave * 32 + m * 16 + lr;
                pf[m][kk] = *reinterpret_cast<const short8*>(
                    Ps + prow * 64 + (((kk * 4 + lq) ^ (lr & 7)) * 8));
            }
#pragma unroll
        for (int kk = 0; kk < 2; ++kk)
#pragma unroll
            for (int m = 0; m < 2; ++m)
#pragma unroll
                for (int dt = 0; dt < 4; ++dt)
                    o[m][dt] = mfma16(pf[m][kk], vf[dt][kk], o[m][dt]);
    }

    // epilogue: reduce l across the 16 col-lanes (lane bits 0-3), normalize
#pragma unroll
    for (int m = 0; m < 2; ++m)
#pragma unroll
        for (int r = 0; r < 4; ++r) {
            float l = lpart[m][r];
            l += __shfl_xor(l, 1);
            l += __shfl_xor(l, 2);
            l += __shfl_xor(l, 4);
            l += __shfl_xor(l, 8);
            float inv = 1.0f / l;
            int t = q0 + wave * 32 + m * 16 + lq * 4 + r;
#pragma unroll
            for (int dt = 0; dt < 4; ++dt) {
                int d = dt * 16 + lr;
                ctx[((size_t)(b * T_SEQ + t)) * C_DIM + h * HD + d] =
                    __float2bfloat16(o[m][dt][r] * inv);
            }
        }
}

// ---------------------------------------------------------------- output GEMM
__global__ __launch_bounds__(256, 2) void gemm_out_kernel(
    const bf16_t* __restrict__ Actx, const bf16_t* __restrict__ WoT,
    const float* __restrict__ bo, float* __restrict__ out) {
    __shared__ bf16_t As[128 * 64];
    __shared__ bf16_t Bs[128 * 64];
    int tid = threadIdx.x, wave = tid >> 6, lane = tid & 63;
    int row0 = blockIdx.y * 128, col0 = blockIdx.x * 128;
    floatx4 acc[4][4] = {};
    gemm_mainloop(Actx + (size_t)row0 * C_DIM, WoT + (size_t)col0 * C_DIM, As, Bs, acc, wave, lane);
    int lr = lane & 15, lq = lane >> 4;
    int wr = (wave >> 1) * 64, wc = (wave & 1) * 64;
#pragma unroll
    for (int nt = 0; nt < 4; ++nt) {
        int col = col0 + wc + nt * 16 + lr;
        float bvv = bo[col];
#pragma unroll
        for (int m = 0; m < 4; ++m)
#pragma unroll
            for (int r = 0; r < 4; ++r) {
                int rowg = row0 + wr + m * 16 + lq * 4 + r;
                out[(size_t)rowg * C_DIM + col] = acc[m][nt][r] + bvv;
            }
    }
}

// ---------------------------------------------------------------- launcher
extern "C" void kernel_launch(void* const* d_in, const int* in_sizes, int n_in,
                              void* d_out, int out_size, void* d_ws, size_t ws_size,
                              hipStream_t stream) {
    const float* x  = (const float*)d_in[0];
    const float* Wq = (const float*)d_in[1];
    const float* bq = (const float*)d_in[2];
    const float* Wk = (const float*)d_in[3];
    const float* bk = (const float*)d_in[4];
    const float* Wv = (const float*)d_in[5];
    const float* bv = (const float*)d_in[6];
    const float* Wo = (const float*)d_in[7];
    const float* bo = (const float*)d_in[8];
    float* out = (float*)d_out;

    char* ws = (char*)d_ws;
    bf16_t* xb  = (bf16_t*)ws; ws += (size_t)M_ROWS * C_DIM * 2;   // 16 MB
    bf16_t* WqT = (bf16_t*)ws; ws += (size_t)C_DIM * C_DIM * 2;    //  2 MB
    bf16_t* WkT = (bf16_t*)ws; ws += (size_t)C_DIM * C_DIM * 2;
    bf16_t* WvT = (bf16_t*)ws; ws += (size_t)C_DIM * C_DIM * 2;
    bf16_t* WoT = (bf16_t*)ws; ws += (size_t)C_DIM * C_DIM * 2;
    bf16_t* Qb  = (bf16_t*)ws; ws += (size_t)M_ROWS * C_DIM * 2;   // [B,H,T,D]
    bf16_t* Kb  = (bf16_t*)ws; ws += (size_t)M_ROWS * C_DIM * 2;   // [B,H,T,D]
    bf16_t* Vtb = (bf16_t*)ws; ws += (size_t)M_ROWS * C_DIM * 2;   // [B,H,D,T]
    bf16_t* ctx = (bf16_t*)ws; ws += (size_t)M_ROWS * C_DIM * 2;   // [B,T,C]

    convert_x_kernel<<<(M_ROWS * C_DIM / 4) / 256, 256, 0, stream>>>(x, xb);
    transpose_cvt_kernel<<<dim3(32, 32, 4), dim3(32, 8), 0, stream>>>(
        Wq, Wk, Wv, Wo, WqT, WkT, WvT, WoT);
    gemm_qkv_kernel<<<dim3(8, 64, 3), 256, 0, stream>>>(
        xb, WqT, WkT, WvT, bq, bk, bv, Qb, Kb, Vtb);
    attn_kernel<<<dim3(16, 64), 256, 0, stream>>>(Qb, Kb, Vtb, ctx);
    gemm_out_kernel<<<dim3(8, 64), 256, 0, stream>>>(ctx, WoT, bo, out);
}

// Round 6
// 300.111 us; speedup vs baseline: 1.7153x; 1.7153x over previous
//
#include <hip/hip_runtime.h>
#include <hip/hip_bf16.h>
#include <math.h>

typedef __hip_bfloat16 bf16_t;
typedef __attribute__((ext_vector_type(8))) short short8;
typedef __attribute__((ext_vector_type(4))) float floatx4;

#define T_SEQ 2048
#define NB    4
#define NH    16
#define HD    64
#define C_DIM 1024
#define M_ROWS (NB * T_SEQ)   // 8192

// Q pre-scale: (1/sqrt(64)) * log2(e) so scores are in log2 units and
// P = exp2(s) directly (unnormalized softmax; shift cancels in O = sum(Pv)/sum(P)).
#define Q_SCALE 0.18033688011f

// ---------------------------------------------------------------- helpers
__device__ __forceinline__ void load_lds16(const bf16_t* g, bf16_t* l) {
    __builtin_amdgcn_global_load_lds(
        (const __attribute__((address_space(1))) void*)g,
        (__attribute__((address_space(3))) void*)l,
        16, 0, 0);
}

__device__ __forceinline__ floatx4 mfma16(short8 a, short8 b, floatx4 c) {
    return __builtin_amdgcn_mfma_f32_16x16x32_bf16(a, b, c, 0, 0, 0);
}

// ---------------------------------------------------------------- converts
__global__ void convert_x_kernel(const float* __restrict__ x, bf16_t* __restrict__ xb) {
    int i = blockIdx.x * 256 + threadIdx.x;   // one float4 per thread
    float4 v = reinterpret_cast<const float4*>(x)[i];
    union { bf16_t h[4]; short4 s4; } u;
    u.h[0] = __float2bfloat16(v.x);
    u.h[1] = __float2bfloat16(v.y);
    u.h[2] = __float2bfloat16(v.z);
    u.h[3] = __float2bfloat16(v.w);
    reinterpret_cast<short4*>(xb)[i] = u.s4;
}

// W [K,N] fp32 -> Wt [N,K] bf16, LDS-tiled transpose. block (32,8), grid (32,32,4)
__global__ void transpose_cvt_kernel(const float* __restrict__ W0, const float* __restrict__ W1,
                                     const float* __restrict__ W2, const float* __restrict__ W3,
                                     bf16_t* __restrict__ O0, bf16_t* __restrict__ O1,
                                     bf16_t* __restrict__ O2, bf16_t* __restrict__ O3) {
    const float* W = (blockIdx.z == 0) ? W0 : (blockIdx.z == 1) ? W1 : (blockIdx.z == 2) ? W2 : W3;
    bf16_t*      O = (blockIdx.z == 0) ? O0 : (blockIdx.z == 1) ? O1 : (blockIdx.z == 2) ? O2 : O3;
    __shared__ float tile[32][33];
    int bx = blockIdx.x * 32, by = blockIdx.y * 32;
    int tx = threadIdx.x, ty = threadIdx.y;
#pragma unroll
    for (int j = 0; j < 32; j += 8)
        tile[ty + j][tx] = W[(size_t)(by + ty + j) * C_DIM + bx + tx];
    __syncthreads();
#pragma unroll
    for (int j = 0; j < 32; j += 8)
        O[(size_t)(bx + ty + j) * C_DIM + by + tx] = __float2bfloat16(tile[tx][ty + j]);
}

// ---------------------------------------------------------------- GEMM mainloop
// C[128,128] += A[128,K] * Bt[128,K]^T  (both row-major, K-contiguous), BK=64.
// LDS layout XOR-swizzled: 16B piece p of row r lives at piece slot (p ^ (r&7)).
__device__ __forceinline__ void gemm_mainloop(const bf16_t* __restrict__ Ablk,
                                              const bf16_t* __restrict__ Bblk,
                                              bf16_t* As, bf16_t* Bs,
                                              floatx4 acc[4][4], int wave, int lane) {
    int lr = lane & 15, lq = lane >> 4;
    int wr = (wave >> 1) * 64, wc = (wave & 1) * 64;
    for (int kt = 0; kt < C_DIM; kt += 64) {
#pragma unroll
        for (int j = 0; j < 4; ++j) {
            int chunk = j * 256 + wave * 64 + lane;       // 0..1023, wave-contiguous
            int r = chunk >> 3, ps = chunk & 7;
            int c = ((ps ^ (r & 7)) * 8);                 // swizzled source column
            load_lds16(Ablk + (size_t)r * C_DIM + kt + c, As + chunk * 8);
            load_lds16(Bblk + (size_t)r * C_DIM + kt + c, Bs + chunk * 8);
        }
        __syncthreads();
#pragma unroll
        for (int kk = 0; kk < 2; ++kk) {
            short8 af[4], bfr[4];
            int psw = ((kk * 4 + lq) ^ (lr & 7)) * 8;     // swizzled piece offset
#pragma unroll
            for (int m = 0; m < 4; ++m)
                af[m] = *reinterpret_cast<const short8*>(As + (wr + m * 16 + lr) * 64 + psw);
#pragma unroll
            for (int n = 0; n < 4; ++n)
                bfr[n] = *reinterpret_cast<const short8*>(Bs + (wc + n * 16 + lr) * 64 + psw);
#pragma unroll
            for (int m = 0; m < 4; ++m)
#pragma unroll
                for (int n = 0; n < 4; ++n)
                    acc[m][n] = mfma16(af[m], bfr[n], acc[m][n]);
        }
        __syncthreads();
    }
}

// ---------------------------------------------------------------- QKV GEMM
// grid (8, 64, 3): z=0 Q (scaled Q_SCALE), z=1 K, z=2 V (transposed store)
// launch_bounds(256,3): cap VGPR ~170 so 3 blocks/CU can be resident.
__global__ __launch_bounds__(256, 3) void gemm_qkv_kernel(
    const bf16_t* __restrict__ xb,
    const bf16_t* __restrict__ WqT, const bf16_t* __restrict__ WkT, const bf16_t* __restrict__ WvT,
    const float* __restrict__ bq, const float* __restrict__ bk, const float* __restrict__ bv,
    bf16_t* __restrict__ Q, bf16_t* __restrict__ K, bf16_t* __restrict__ Vt) {
    __shared__ bf16_t As[128 * 64];
    __shared__ bf16_t Bs[128 * 64];
    int tid = threadIdx.x, wave = tid >> 6, lane = tid & 63;
    int row0 = blockIdx.y * 128, col0 = blockIdx.x * 128;
    int wsel = blockIdx.z;
    const bf16_t* Wt  = (wsel == 0) ? WqT : (wsel == 1) ? WkT : WvT;
    const float* bias = (wsel == 0) ? bq : (wsel == 1) ? bk : bv;

    floatx4 acc[4][4] = {};
    gemm_mainloop(xb + (size_t)row0 * C_DIM, Wt + (size_t)col0 * C_DIM, As, Bs, acc, wave, lane);

    int lr = lane & 15, lq = lane >> 4;
    int wr = (wave >> 1) * 64, wc = (wave & 1) * 64;
    float scale = (wsel == 0) ? Q_SCALE : 1.0f;
    bf16_t* outp = (wsel == 0) ? Q : (wsel == 1) ? K : Vt;
    bool vtrans = (wsel == 2);
#pragma unroll
    for (int nt = 0; nt < 4; ++nt) {
        int col = col0 + wc + nt * 16 + lr;
        float bvv = bias[col];
        int h = col >> 6, d = col & 63;
#pragma unroll
        for (int m = 0; m < 4; ++m) {
#pragma unroll
            for (int r = 0; r < 4; ++r) {
                int rowg = row0 + wr + m * 16 + lq * 4 + r;
                int b = rowg >> 11, t = rowg & (T_SEQ - 1);
                float val = (acc[m][nt][r] + bvv) * scale;
                size_t idx = vtrans
                    ? ((size_t)((b * NH + h) * HD + d)) * T_SEQ + t
                    : ((size_t)((b * NH + h) * T_SEQ + t)) * HD + d;
                outp[idx] = __float2bfloat16(val);
            }
        }
    }
}

// ---------------------------------------------------------------- attention
// grid (8, 64), block 512 threads = 8 waves; each wave owns 16 q-rows of a
// 128-row q-tile. Each block does TWO q-tiles (qt = 15-x then x) -> uniform
// work; 512 blocks = 2 resident/CU = 16 waves/CU (4/SIMD). LDS-staged,
// double-buffered K/V (register-cheap — round-5 lesson: direct global frags
// spill). Unnormalized softmax: P = exp2(s) (Q pre-scaled by log2e/8), no
// running max, per-lane l partials reduced once per pass. Swizzled LDS
// (measured conflict-free in this exact addressing pattern).
__global__ __launch_bounds__(512, 4) void attn_kernel(
    const bf16_t* __restrict__ Q, const bf16_t* __restrict__ K,
    const bf16_t* __restrict__ Vt, bf16_t* __restrict__ ctx) {
    __shared__ __align__(16) bf16_t Ks[2][64 * 64];   // K tile  [k][d], swizzled
    __shared__ __align__(16) bf16_t Vs[2][64 * 64];   // Vt tile [d][k], swizzled
    __shared__ __align__(16) bf16_t Ps[128 * 64];     // P tile  [q][k], swizzled
    int tid = threadIdx.x, w = tid >> 6, lane = tid & 63;
    int lr = lane & 15, lq = lane >> 4;
    int bh = blockIdx.y;
    int b = bh >> 4, h = bh & 15;

    const bf16_t* Kbase = K  + (size_t)bh * T_SEQ * HD;
    const bf16_t* Vbase = Vt + (size_t)bh * HD * T_SEQ;

#pragma unroll 1
    for (int pass = 0; pass < 2; ++pass) {
        int qt = pass ? (int)blockIdx.x : (15 - (int)blockIdx.x);
        int q0 = qt * 128;
        int ktiles = 2 * qt + 2;                      // always even
        const bf16_t* Qbase = Q + ((size_t)bh * T_SEQ + q0) * HD;

        // stage tile 0 into buffer 0 (512 threads: 1 chunk each for K and V).
        // Safe vs pass-0 stragglers: their last iteration reads buffer 1.
        {
            int ch = tid;
            int r = ch >> 3, ps = ch & 7;
            int c = ((ps ^ (r & 7)) * 8);
            load_lds16(Kbase + (size_t)r * HD + c, Ks[0] + ch * 8);
            load_lds16(Vbase + (size_t)r * T_SEQ + c, Vs[0] + ch * 8);
        }

        // Q fragments in registers: wave w owns rows [w*16, w*16+16)
        short8 qf[2];
#pragma unroll
        for (int kk = 0; kk < 2; ++kk)
            qf[kk] = *reinterpret_cast<const short8*>(
                Qbase + (size_t)(w * 16 + lr) * HD + kk * 32 + lq * 8);

        floatx4 o[4] = {};
        float lpart[4] = {};
        int buf = 0;

        for (int it = 0; it < ktiles; ++it) {
            int kt0 = it * 64;
            __syncthreads();   // drains stage(it) vmcnt; protects both buffers

            // prefetch next tile — drains at NEXT barrier (overlaps this compute)
            if (it + 1 < ktiles) {
                int nk0 = kt0 + 64;
                int ch = tid;
                int r = ch >> 3, ps = ch & 7;
                int c = ((ps ^ (r & 7)) * 8);
                load_lds16(Kbase + (size_t)(nk0 + r) * HD + c, Ks[buf ^ 1] + ch * 8);
                load_lds16(Vbase + (size_t)r * T_SEQ + nk0 + c, Vs[buf ^ 1] + ch * 8);
            }

            const bf16_t* Kc = Ks[buf];
            const bf16_t* Vc = Vs[buf];

            // S = Q K^T (log2 units)
            floatx4 s[4] = {};
            short8 kf[4][2];
#pragma unroll
            for (int kk = 0; kk < 2; ++kk) {
                int psw = ((kk * 4 + lq) ^ (lr & 7)) * 8;
#pragma unroll
                for (int n = 0; n < 4; ++n)
                    kf[n][kk] = *reinterpret_cast<const short8*>(Kc + (n * 16 + lr) * 64 + psw);
            }
#pragma unroll
            for (int kk = 0; kk < 2; ++kk)
#pragma unroll
                for (int n = 0; n < 4; ++n)
                    s[n] = mfma16(qf[kk], kf[n][kk], s[n]);

            // causal mask only on the last two tiles (block-uniform branch)
            if (it >= ktiles - 2) {
#pragma unroll
                for (int r = 0; r < 4; ++r) {
                    int rowg = q0 + w * 16 + lq * 4 + r;
#pragma unroll
                    for (int n = 0; n < 4; ++n) {
                        int colg = kt0 + n * 16 + lr;
                        if (colg > rowg) s[n][r] = -1e30f;
                    }
                }
            }

            // P = exp2(s); accumulate per-lane l partials (no cross-lane ops)
#pragma unroll
            for (int n = 0; n < 4; ++n)
#pragma unroll
                for (int r = 0; r < 4; ++r)
                    s[n][r] = exp2f(s[n][r]);
#pragma unroll
            for (int r = 0; r < 4; ++r)
                lpart[r] += (s[0][r] + s[1][r]) + (s[2][r] + s[3][r]);

            // dump P to LDS (C-layout -> A-layout; rows are wave-private,
            // lgkmcnt orders wave-local write->read, no barrier needed)
#pragma unroll
            for (int n = 0; n < 4; ++n)
#pragma unroll
                for (int r = 0; r < 4; ++r) {
                    int prow = w * 16 + lq * 4 + r;
                    int piece = n * 2 + (lr >> 3);
                    Ps[prow * 64 + ((piece ^ (prow & 7)) * 8) + (lr & 7)] =
                        __float2bfloat16(s[n][r]);
                }

            // O += P V
            short8 pf[2], vf[4][2];
#pragma unroll
            for (int kk = 0; kk < 2; ++kk) {
                int prow = w * 16 + lr;
                pf[kk] = *reinterpret_cast<const short8*>(
                    Ps + prow * 64 + (((kk * 4 + lq) ^ (lr & 7)) * 8));
            }
#pragma unroll
            for (int kk = 0; kk < 2; ++kk) {
                int psw = ((kk * 4 + lq) ^ (lr & 7)) * 8;
#pragma unroll
                for (int dt = 0; dt < 4; ++dt)
                    vf[dt][kk] = *reinterpret_cast<const short8*>(Vc + (dt * 16 + lr) * 64 + psw);
            }
#pragma unroll
            for (int kk = 0; kk < 2; ++kk)
#pragma unroll
                for (int dt = 0; dt < 4; ++dt)
                    o[dt] = mfma16(pf[kk], vf[dt][kk], o[dt]);

            buf ^= 1;
        }

        // epilogue: reduce l across the 16 col-lanes (lane bits 0-3), normalize
#pragma unroll
        for (int r = 0; r < 4; ++r) {
            float l = lpart[r];
            l += __shfl_xor(l, 1);
            l += __shfl_xor(l, 2);
            l += __shfl_xor(l, 4);
            l += __shfl_xor(l, 8);
            float inv = 1.0f / l;
            int t = q0 + w * 16 + lq * 4 + r;
#pragma unroll
            for (int dt = 0; dt < 4; ++dt) {
                int d = dt * 16 + lr;
                ctx[((size_t)(b * T_SEQ + t)) * C_DIM + h * HD + d] =
                    __float2bfloat16(o[dt][r] * inv);
            }
        }
    }
}

// ---------------------------------------------------------------- output GEMM
__global__ __launch_bounds__(256, 3) void gemm_out_kernel(
    const bf16_t* __restrict__ Actx, const bf16_t* __restrict__ WoT,
    const float* __restrict__ bo, float* __restrict__ out) {
    __shared__ bf16_t As[128 * 64];
    __shared__ bf16_t Bs[128 * 64];
    int tid = threadIdx.x, wave = tid >> 6, lane = tid & 63;
    int row0 = blockIdx.y * 128, col0 = blockIdx.x * 128;
    floatx4 acc[4][4] = {};
    gemm_mainloop(Actx + (size_t)row0 * C_DIM, WoT + (size_t)col0 * C_DIM, As, Bs, acc, wave, lane);
    int lr = lane & 15, lq = lane >> 4;
    int wr = (wave >> 1) * 64, wc = (wave & 1) * 64;
#pragma unroll
    for (int nt = 0; nt < 4; ++nt) {
        int col = col0 + wc + nt * 16 + lr;
        float bvv = bo[col];
#pragma unroll
        for (int m = 0; m < 4; ++m)
#pragma unroll
            for (int r = 0; r < 4; ++r) {
                int rowg = row0 + wr + m * 16 + lq * 4 + r;
                out[(size_t)rowg * C_DIM + col] = acc[m][nt][r] + bvv;
            }
    }
}

// ---------------------------------------------------------------- launcher
extern "C" void kernel_launch(void* const* d_in, const int* in_sizes, int n_in,
                              void* d_out, int out_size, void* d_ws, size_t ws_size,
                              hipStream_t stream) {
    const float* x  = (const float*)d_in[0];
    const float* Wq = (const float*)d_in[1];
    const float* bq = (const float*)d_in[2];
    const float* Wk = (const float*)d_in[3];
    const float* bk = (const float*)d_in[4];
    const float* Wv = (const float*)d_in[5];
    const float* bv = (const float*)d_in[6];
    const float* Wo = (const float*)d_in[7];
    const float* bo = (const float*)d_in[8];
    float* out = (float*)d_out;

    char* ws = (char*)d_ws;
    bf16_t* xb  = (bf16_t*)ws; ws += (size_t)M_ROWS * C_DIM * 2;   // 16 MB
    bf16_t* WqT = (bf16_t*)ws; ws += (size_t)C_DIM * C_DIM * 2;    //  2 MB
    bf16_t* WkT = (bf16_t*)ws; ws += (size_t)C_DIM * C_DIM * 2;
    bf16_t* WvT = (bf16_t*)ws; ws += (size_t)C_DIM * C_DIM * 2;
    bf16_t* WoT = (bf16_t*)ws; ws += (size_t)C_DIM * C_DIM * 2;
    bf16_t* Qb  = (bf16_t*)ws; ws += (size_t)M_ROWS * C_DIM * 2;   // [B,H,T,D]
    bf16_t* Kb  = (bf16_t*)ws; ws += (size_t)M_ROWS * C_DIM * 2;   // [B,H,T,D]
    bf16_t* Vtb = (bf16_t*)ws; ws += (size_t)M_ROWS * C_DIM * 2;   // [B,H,D,T]
    bf16_t* ctx = (bf16_t*)ws; ws += (size_t)M_ROWS * C_DIM * 2;   // [B,T,C]

    convert_x_kernel<<<(M_ROWS * C_DIM / 4) / 256, 256, 0, stream>>>(x, xb);
    transpose_cvt_kernel<<<dim3(32, 32, 4), dim3(32, 8), 0, stream>>>(
        Wq, Wk, Wv, Wo, WqT, WkT, WvT, WoT);
    gemm_qkv_kernel<<<dim3(8, 64, 3), 256, 0, stream>>>(
        xb, WqT, WkT, WvT, bq, bk, bv, Qb, Kb, Vtb);
    attn_kernel<<<dim3(8, 64), 512, 0, stream>>>(Qb, Kb, Vtb, ctx);
    gemm_out_kernel<<<dim3(8, 64), 256, 0, stream>>>(ctx, WoT, bo, out);
}

// Round 7
// 249.316 us; speedup vs baseline: 2.0648x; 1.2037x over previous
//
#include <hip/hip_runtime.h>
#include <hip/hip_bf16.h>
#include <math.h>

typedef __hip_bfloat16 bf16_t;
typedef __attribute__((ext_vector_type(8))) short short8;
typedef __attribute__((ext_vector_type(4))) float floatx4;

#define T_SEQ 2048
#define NB    4
#define NH    16
#define HD    64
#define C_DIM 1024
#define M_ROWS (NB * T_SEQ)   // 8192

// Q pre-scale: (1/sqrt(64)) * log2(e) so scores are in log2 units and
// P = exp2(s) directly (unnormalized softmax; shift cancels in O = sum(Pv)/sum(P)).
#define Q_SCALE 0.18033688011f

// ---------------------------------------------------------------- helpers
__device__ __forceinline__ void load_lds16(const bf16_t* g, bf16_t* l) {
    __builtin_amdgcn_global_load_lds(
        (const __attribute__((address_space(1))) void*)g,
        (__attribute__((address_space(3))) void*)l,
        16, 0, 0);
}

__device__ __forceinline__ floatx4 mfma16(short8 a, short8 b, floatx4 c) {
    return __builtin_amdgcn_mfma_f32_16x16x32_bf16(a, b, c, 0, 0, 0);
}

// ---------------------------------------------------------------- converts
__global__ void convert_x_kernel(const float* __restrict__ x, bf16_t* __restrict__ xb) {
    int i = blockIdx.x * 256 + threadIdx.x;   // one float4 per thread
    float4 v = reinterpret_cast<const float4*>(x)[i];
    union { bf16_t h[4]; short4 s4; } u;
    u.h[0] = __float2bfloat16(v.x);
    u.h[1] = __float2bfloat16(v.y);
    u.h[2] = __float2bfloat16(v.z);
    u.h[3] = __float2bfloat16(v.w);
    reinterpret_cast<short4*>(xb)[i] = u.s4;
}

// W [K,N] fp32 -> Wt [N,K] bf16, LDS-tiled transpose. block (32,8), grid (32,32,4)
__global__ void transpose_cvt_kernel(const float* __restrict__ W0, const float* __restrict__ W1,
                                     const float* __restrict__ W2, const float* __restrict__ W3,
                                     bf16_t* __restrict__ O0, bf16_t* __restrict__ O1,
                                     bf16_t* __restrict__ O2, bf16_t* __restrict__ O3) {
    const float* W = (blockIdx.z == 0) ? W0 : (blockIdx.z == 1) ? W1 : (blockIdx.z == 2) ? W2 : W3;
    bf16_t*      O = (blockIdx.z == 0) ? O0 : (blockIdx.z == 1) ? O1 : (blockIdx.z == 2) ? O2 : O3;
    __shared__ float tile[32][33];
    int bx = blockIdx.x * 32, by = blockIdx.y * 32;
    int tx = threadIdx.x, ty = threadIdx.y;
#pragma unroll
    for (int j = 0; j < 32; j += 8)
        tile[ty + j][tx] = W[(size_t)(by + ty + j) * C_DIM + bx + tx];
    __syncthreads();
#pragma unroll
    for (int j = 0; j < 32; j += 8)
        O[(size_t)(bx + ty + j) * C_DIM + by + tx] = __float2bfloat16(tile[tx][ty + j]);
}

// ---------------------------------------------------------------- GEMM mainloop
// C[128,128] += A[128,K] * Bt[128,K]^T  (both row-major, K-contiguous), BK=64.
// LDS layout XOR-swizzled: 16B piece p of row r lives at piece slot (p ^ (r&7)).
__device__ __forceinline__ void gemm_mainloop(const bf16_t* __restrict__ Ablk,
                                              const bf16_t* __restrict__ Bblk,
                                              bf16_t* As, bf16_t* Bs,
                                              floatx4 acc[4][4], int wave, int lane) {
    int lr = lane & 15, lq = lane >> 4;
    int wr = (wave >> 1) * 64, wc = (wave & 1) * 64;
    for (int kt = 0; kt < C_DIM; kt += 64) {
#pragma unroll
        for (int j = 0; j < 4; ++j) {
            int chunk = j * 256 + wave * 64 + lane;       // 0..1023, wave-contiguous
            int r = chunk >> 3, ps = chunk & 7;
            int c = ((ps ^ (r & 7)) * 8);                 // swizzled source column
            load_lds16(Ablk + (size_t)r * C_DIM + kt + c, As + chunk * 8);
            load_lds16(Bblk + (size_t)r * C_DIM + kt + c, Bs + chunk * 8);
        }
        __syncthreads();
#pragma unroll
        for (int kk = 0; kk < 2; ++kk) {
            short8 af[4], bfr[4];
            int psw = ((kk * 4 + lq) ^ (lr & 7)) * 8;     // swizzled piece offset
#pragma unroll
            for (int m = 0; m < 4; ++m)
                af[m] = *reinterpret_cast<const short8*>(As + (wr + m * 16 + lr) * 64 + psw);
#pragma unroll
            for (int n = 0; n < 4; ++n)
                bfr[n] = *reinterpret_cast<const short8*>(Bs + (wc + n * 16 + lr) * 64 + psw);
#pragma unroll
            for (int m = 0; m < 4; ++m)
#pragma unroll
                for (int n = 0; n < 4; ++n)
                    acc[m][n] = mfma16(af[m], bfr[n], acc[m][n]);
        }
        __syncthreads();
    }
}

// ---------------------------------------------------------------- QKV GEMM
// grid (8, 64, 3). Block->tile mapping is XCD-swizzled: f = x + 8y + 512z,
// xcd = f&7 owns row-panels [8*xcd, 8*xcd+8). Within an XCD, the A-panel
// index cycles FASTEST (8 consecutive per-XCD blocks sweep all 8 A-panels
// with one W-panel) -> A (2 MB) stays L2-resident, W panels stream once.
// Fixes round-6's 180 MB fetch (8 XCDs each refetching all A panels).
__global__ __launch_bounds__(256, 3) void gemm_qkv_kernel(
    const bf16_t* __restrict__ xb,
    const bf16_t* __restrict__ WqT, const bf16_t* __restrict__ WkT, const bf16_t* __restrict__ WvT,
    const float* __restrict__ bq, const float* __restrict__ bk, const float* __restrict__ bv,
    bf16_t* __restrict__ Q, bf16_t* __restrict__ K, bf16_t* __restrict__ Vt) {
    __shared__ bf16_t As[128 * 64];
    __shared__ bf16_t Bs[128 * 64];
    int tid = threadIdx.x, wave = tid >> 6, lane = tid & 63;

    int f    = (int)blockIdx.x + ((int)blockIdx.y << 3) + ((int)blockIdx.z << 9);
    int xcd  = f & 7;
    int s    = f >> 3;          // 0..191 per-XCD sequence
    int rloc = s & 7;           // A-panel: fastest
    int t2   = s >> 3;          // 0..23
    int colp = t2 & 7;          // W-panel
    int wsel = t2 >> 3;         // 0..2: z outermost per XCD
    int row0 = (xcd * 8 + rloc) * 128;
    int col0 = colp * 128;

    const bf16_t* Wt  = (wsel == 0) ? WqT : (wsel == 1) ? WkT : WvT;
    const float* bias = (wsel == 0) ? bq : (wsel == 1) ? bk : bv;

    floatx4 acc[4][4] = {};
    gemm_mainloop(xb + (size_t)row0 * C_DIM, Wt + (size_t)col0 * C_DIM, As, Bs, acc, wave, lane);

    int lr = lane & 15, lq = lane >> 4;
    int wr = (wave >> 1) * 64, wc = (wave & 1) * 64;

    if (wsel == 2) {
        // V transposed store, packed: r=0..3 are 4 consecutive t for fixed d
        // -> one short4 (8B) store instead of 4 scalar 2B stores.
#pragma unroll
        for (int nt = 0; nt < 4; ++nt) {
            int col = col0 + wc + nt * 16 + lr;
            float bvv = bias[col];
            int h = col >> 6, d = col & 63;
#pragma unroll
            for (int m = 0; m < 4; ++m) {
                int rowg0 = row0 + wr + m * 16 + lq * 4;
                int b = rowg0 >> 11, t0 = rowg0 & (T_SEQ - 1);
                union { bf16_t h4[4]; short4 s4; } u;
#pragma unroll
                for (int r = 0; r < 4; ++r)
                    u.h4[r] = __float2bfloat16(acc[m][nt][r] + bvv);
                *reinterpret_cast<short4*>(
                    &Vt[((size_t)((b * NH + h) * HD + d)) * T_SEQ + t0]) = u.s4;
            }
        }
    } else {
        float scale = (wsel == 0) ? Q_SCALE : 1.0f;
        bf16_t* outp = (wsel == 0) ? Q : K;
#pragma unroll
        for (int nt = 0; nt < 4; ++nt) {
            int col = col0 + wc + nt * 16 + lr;
            float bvv = bias[col];
            int h = col >> 6, d = col & 63;
#pragma unroll
            for (int m = 0; m < 4; ++m) {
#pragma unroll
                for (int r = 0; r < 4; ++r) {
                    int rowg = row0 + wr + m * 16 + lq * 4 + r;
                    int b = rowg >> 11, t = rowg & (T_SEQ - 1);
                    float val = (acc[m][nt][r] + bvv) * scale;
                    outp[((size_t)((b * NH + h) * T_SEQ + t)) * HD + d] =
                        __float2bfloat16(val);
                }
            }
        }
    }
}

// ---------------------------------------------------------------- attention
// grid (8, 64), block 512 threads = 8 waves; each wave owns 16 q-rows of a
// 128-row q-tile. Each block does TWO q-tiles (qt = 15-x then x) -> uniform
// work; 512 blocks = 2 resident/CU = 16 waves/CU (4/SIMD). LDS-staged,
// double-buffered K/V (register-cheap — round-5 lesson: direct global frags
// spill). Unnormalized softmax: P = exp2(s) (Q pre-scaled by log2e/8), no
// running max, per-lane l partials reduced once per pass. Swizzled LDS
// (measured conflict-free in this exact addressing pattern).
__global__ __launch_bounds__(512, 4) void attn_kernel(
    const bf16_t* __restrict__ Q, const bf16_t* __restrict__ K,
    const bf16_t* __restrict__ Vt, bf16_t* __restrict__ ctx) {
    __shared__ __align__(16) bf16_t Ks[2][64 * 64];   // K tile  [k][d], swizzled
    __shared__ __align__(16) bf16_t Vs[2][64 * 64];   // Vt tile [d][k], swizzled
    __shared__ __align__(16) bf16_t Ps[128 * 64];     // P tile  [q][k], swizzled
    int tid = threadIdx.x, w = tid >> 6, lane = tid & 63;
    int lr = lane & 15, lq = lane >> 4;
    int bh = blockIdx.y;
    int b = bh >> 4, h = bh & 15;

    const bf16_t* Kbase = K  + (size_t)bh * T_SEQ * HD;
    const bf16_t* Vbase = Vt + (size_t)bh * HD * T_SEQ;

#pragma unroll 1
    for (int pass = 0; pass < 2; ++pass) {
        int qt = pass ? (int)blockIdx.x : (15 - (int)blockIdx.x);
        int q0 = qt * 128;
        int ktiles = 2 * qt + 2;                      // always even
        const bf16_t* Qbase = Q + ((size_t)bh * T_SEQ + q0) * HD;

        // stage tile 0 into buffer 0 (512 threads: 1 chunk each for K and V).
        // Safe vs pass-0 stragglers: their last iteration reads buffer 1.
        {
            int ch = tid;
            int r = ch >> 3, ps = ch & 7;
            int c = ((ps ^ (r & 7)) * 8);
            load_lds16(Kbase + (size_t)r * HD + c, Ks[0] + ch * 8);
            load_lds16(Vbase + (size_t)r * T_SEQ + c, Vs[0] + ch * 8);
        }

        // Q fragments in registers: wave w owns rows [w*16, w*16+16)
        short8 qf[2];
#pragma unroll
        for (int kk = 0; kk < 2; ++kk)
            qf[kk] = *reinterpret_cast<const short8*>(
                Qbase + (size_t)(w * 16 + lr) * HD + kk * 32 + lq * 8);

        floatx4 o[4] = {};
        float lpart[4] = {};
        int buf = 0;

        for (int it = 0; it < ktiles; ++it) {
            int kt0 = it * 64;
            __syncthreads();   // drains stage(it) vmcnt; protects both buffers

            // prefetch next tile — drains at NEXT barrier (overlaps this compute)
            if (it + 1 < ktiles) {
                int nk0 = kt0 + 64;
                int ch = tid;
                int r = ch >> 3, ps = ch & 7;
                int c = ((ps ^ (r & 7)) * 8);
                load_lds16(Kbase + (size_t)(nk0 + r) * HD + c, Ks[buf ^ 1] + ch * 8);
                load_lds16(Vbase + (size_t)r * T_SEQ + nk0 + c, Vs[buf ^ 1] + ch * 8);
            }

            const bf16_t* Kc = Ks[buf];
            const bf16_t* Vc = Vs[buf];

            // S = Q K^T (log2 units)
            floatx4 s[4] = {};
            short8 kf[4][2];
#pragma unroll
            for (int kk = 0; kk < 2; ++kk) {
                int psw = ((kk * 4 + lq) ^ (lr & 7)) * 8;
#pragma unroll
                for (int n = 0; n < 4; ++n)
                    kf[n][kk] = *reinterpret_cast<const short8*>(Kc + (n * 16 + lr) * 64 + psw);
            }
#pragma unroll
            for (int kk = 0; kk < 2; ++kk)
#pragma unroll
                for (int n = 0; n < 4; ++n)
                    s[n] = mfma16(qf[kk], kf[n][kk], s[n]);

            // causal mask only on the last two tiles (block-uniform branch)
            if (it >= ktiles - 2) {
#pragma unroll
                for (int r = 0; r < 4; ++r) {
                    int rowg = q0 + w * 16 + lq * 4 + r;
#pragma unroll
                    for (int n = 0; n < 4; ++n) {
                        int colg = kt0 + n * 16 + lr;
                        if (colg > rowg) s[n][r] = -1e30f;
                    }
                }
            }

            // P = exp2(s); accumulate per-lane l partials (no cross-lane ops)
#pragma unroll
            for (int n = 0; n < 4; ++n)
#pragma unroll
                for (int r = 0; r < 4; ++r)
                    s[n][r] = exp2f(s[n][r]);
#pragma unroll
            for (int r = 0; r < 4; ++r)
                lpart[r] += (s[0][r] + s[1][r]) + (s[2][r] + s[3][r]);

            // dump P to LDS (C-layout -> A-layout; rows are wave-private,
            // lgkmcnt orders wave-local write->read, no barrier needed)
#pragma unroll
            for (int n = 0; n < 4; ++n)
#pragma unroll
                for (int r = 0; r < 4; ++r) {
                    int prow = w * 16 + lq * 4 + r;
                    int piece = n * 2 + (lr >> 3);
                    Ps[prow * 64 + ((piece ^ (prow & 7)) * 8) + (lr & 7)] =
                        __float2bfloat16(s[n][r]);
                }

            // O += P V
            short8 pf[2], vf[4][2];
#pragma unroll
            for (int kk = 0; kk < 2; ++kk) {
                int prow = w * 16 + lr;
                pf[kk] = *reinterpret_cast<const short8*>(
                    Ps + prow * 64 + (((kk * 4 + lq) ^ (lr & 7)) * 8));
            }
#pragma unroll
            for (int kk = 0; kk < 2; ++kk) {
                int psw = ((kk * 4 + lq) ^ (lr & 7)) * 8;
#pragma unroll
                for (int dt = 0; dt < 4; ++dt)
                    vf[dt][kk] = *reinterpret_cast<const short8*>(Vc + (dt * 16 + lr) * 64 + psw);
            }
#pragma unroll
            for (int kk = 0; kk < 2; ++kk)
#pragma unroll
                for (int dt = 0; dt < 4; ++dt)
                    o[dt] = mfma16(pf[kk], vf[dt][kk], o[dt]);

            buf ^= 1;
        }

        // epilogue: reduce l across the 16 col-lanes (lane bits 0-3), normalize
#pragma unroll
        for (int r = 0; r < 4; ++r) {
            float l = lpart[r];
            l += __shfl_xor(l, 1);
            l += __shfl_xor(l, 2);
            l += __shfl_xor(l, 4);
            l += __shfl_xor(l, 8);
            float inv = 1.0f / l;
            int t = q0 + w * 16 + lq * 4 + r;
#pragma unroll
            for (int dt = 0; dt < 4; ++dt) {
                int d = dt * 16 + lr;
                ctx[((size_t)(b * T_SEQ + t)) * C_DIM + h * HD + d] =
                    __float2bfloat16(o[dt][r] * inv);
            }
        }
    }
}

// ---------------------------------------------------------------- output GEMM
// grid (8, 64), XCD-swizzled like gemm_qkv: xcd owns 8 row-panels, A-panel
// fastest within XCD -> ctx rows L2-resident, WoT streamed once per XCD.
__global__ __launch_bounds__(256, 3) void gemm_out_kernel(
    const bf16_t* __restrict__ Actx, const bf16_t* __restrict__ WoT,
    const float* __restrict__ bo, float* __restrict__ out) {
    __shared__ bf16_t As[128 * 64];
    __shared__ bf16_t Bs[128 * 64];
    int tid = threadIdx.x, wave = tid >> 6, lane = tid & 63;

    int f    = (int)blockIdx.x + ((int)blockIdx.y << 3);
    int xcd  = f & 7;
    int s    = f >> 3;          // 0..63
    int rloc = s & 7;           // A-panel: fastest
    int colp = s >> 3;          // 0..7
    int row0 = (xcd * 8 + rloc) * 128;
    int col0 = colp * 128;

    floatx4 acc[4][4] = {};
    gemm_mainloop(Actx + (size_t)row0 * C_DIM, WoT + (size_t)col0 * C_DIM, As, Bs, acc, wave, lane);
    int lr = lane & 15, lq = lane >> 4;
    int wr = (wave >> 1) * 64, wc = (wave & 1) * 64;
#pragma unroll
    for (int nt = 0; nt < 4; ++nt) {
        int col = col0 + wc + nt * 16 + lr;
        float bvv = bo[col];
#pragma unroll
        for (int m = 0; m < 4; ++m)
#pragma unroll
            for (int r = 0; r < 4; ++r) {
                int rowg = row0 + wr + m * 16 + lq * 4 + r;
                out[(size_t)rowg * C_DIM + col] = acc[m][nt][r] + bvv;
            }
    }
}

// ---------------------------------------------------------------- launcher
extern "C" void kernel_launch(void* const* d_in, const int* in_sizes, int n_in,
                              void* d_out, int out_size, void* d_ws, size_t ws_size,
                              hipStream_t stream) {
    const float* x  = (const float*)d_in[0];
    const float* Wq = (const float*)d_in[1];
    const float* bq = (const float*)d_in[2];
    const float* Wk = (const float*)d_in[3];
    const float* bk = (const float*)d_in[4];
    const float* Wv = (const float*)d_in[5];
    const float* bv = (const float*)d_in[6];
    const float* Wo = (const float*)d_in[7];
    const float* bo = (const float*)d_in[8];
    float* out = (float*)d_out;

    char* ws = (char*)d_ws;
    bf16_t* xb  = (bf16_t*)ws; ws += (size_t)M_ROWS * C_DIM * 2;   // 16 MB
    bf16_t* WqT = (bf16_t*)ws; ws += (size_t)C_DIM * C_DIM * 2;    //  2 MB
    bf16_t* WkT = (bf16_t*)ws; ws += (size_t)C_DIM * C_DIM * 2;
    bf16_t* WvT = (bf16_t*)ws; ws += (size_t)C_DIM * C_DIM * 2;
    bf16_t* WoT = (bf16_t*)ws; ws += (size_t)C_DIM * C_DIM * 2;
    bf16_t* Qb  = (bf16_t*)ws; ws += (size_t)M_ROWS * C_DIM * 2;   // [B,H,T,D]
    bf16_t* Kb  = (bf16_t*)ws; ws += (size_t)M_ROWS * C_DIM * 2;   // [B,H,T,D]
    bf16_t* Vtb = (bf16_t*)ws; ws += (size_t)M_ROWS * C_DIM * 2;   // [B,H,D,T]
    bf16_t* ctx = (bf16_t*)ws; ws += (size_t)M_ROWS * C_DIM * 2;   // [B,T,C]

    convert_x_kernel<<<(M_ROWS * C_DIM / 4) / 256, 256, 0, stream>>>(x, xb);
    transpose_cvt_kernel<<<dim3(32, 32, 4), dim3(32, 8), 0, stream>>>(
        Wq, Wk, Wv, Wo, WqT, WkT, WvT, WoT);
    gemm_qkv_kernel<<<dim3(8, 64, 3), 256, 0, stream>>>(
        xb, WqT, WkT, WvT, bq, bk, bv, Qb, Kb, Vtb);
    attn_kernel<<<dim3(8, 64), 512, 0, stream>>>(Qb, Kb, Vtb, ctx);
    gemm_out_kernel<<<dim3(8, 64), 256, 0, stream>>>(ctx, WoT, bo, out);
}

// Round 8
// 245.364 us; speedup vs baseline: 2.0980x; 1.0161x over previous
//
#include <hip/hip_runtime.h>
#include <hip/hip_bf16.h>
#include <math.h>

typedef __hip_bfloat16 bf16_t;
typedef __attribute__((ext_vector_type(8))) short short8;
typedef __attribute__((ext_vector_type(4))) float floatx4;

#define T_SEQ 2048
#define NB    4
#define NH    16
#define HD    64
#define C_DIM 1024
#define M_ROWS (NB * T_SEQ)   // 8192

// Q pre-scale: (1/sqrt(64)) * log2(e) so scores are in log2 units and
// P = exp2(s) directly (unnormalized softmax; shift cancels in O = sum(Pv)/sum(P)).
#define Q_SCALE 0.18033688011f

// ---------------------------------------------------------------- helpers
__device__ __forceinline__ void load_lds16(const bf16_t* g, bf16_t* l) {
    __builtin_amdgcn_global_load_lds(
        (const __attribute__((address_space(1))) void*)g,
        (__attribute__((address_space(3))) void*)l,
        16, 0, 0);
}

__device__ __forceinline__ floatx4 mfma16(short8 a, short8 b, floatx4 c) {
    return __builtin_amdgcn_mfma_f32_16x16x32_bf16(a, b, c, 0, 0, 0);
}

// ---------------------------------------------------------------- converts
__global__ void convert_x_kernel(const float* __restrict__ x, bf16_t* __restrict__ xb) {
    int i = blockIdx.x * 256 + threadIdx.x;   // one float4 per thread
    float4 v = reinterpret_cast<const float4*>(x)[i];
    union { bf16_t h[4]; short4 s4; } u;
    u.h[0] = __float2bfloat16(v.x);
    u.h[1] = __float2bfloat16(v.y);
    u.h[2] = __float2bfloat16(v.z);
    u.h[3] = __float2bfloat16(v.w);
    reinterpret_cast<short4*>(xb)[i] = u.s4;
}

// W [K,N] fp32 -> Wt [N,K] bf16, LDS-tiled transpose. block (32,8), grid (32,32,4)
__global__ void transpose_cvt_kernel(const float* __restrict__ W0, const float* __restrict__ W1,
                                     const float* __restrict__ W2, const float* __restrict__ W3,
                                     bf16_t* __restrict__ O0, bf16_t* __restrict__ O1,
                                     bf16_t* __restrict__ O2, bf16_t* __restrict__ O3) {
    const float* W = (blockIdx.z == 0) ? W0 : (blockIdx.z == 1) ? W1 : (blockIdx.z == 2) ? W2 : W3;
    bf16_t*      O = (blockIdx.z == 0) ? O0 : (blockIdx.z == 1) ? O1 : (blockIdx.z == 2) ? O2 : O3;
    __shared__ float tile[32][33];
    int bx = blockIdx.x * 32, by = blockIdx.y * 32;
    int tx = threadIdx.x, ty = threadIdx.y;
#pragma unroll
    for (int j = 0; j < 32; j += 8)
        tile[ty + j][tx] = W[(size_t)(by + ty + j) * C_DIM + bx + tx];
    __syncthreads();
#pragma unroll
    for (int j = 0; j < 32; j += 8)
        O[(size_t)(bx + ty + j) * C_DIM + by + tx] = __float2bfloat16(tile[tx][ty + j]);
}

// ---------------------------------------------------------------- GEMM mainloop
// C[128,128] += A[128,K] * Bt[128,K]^T  (both row-major, K-contiguous), BK=64.
// LDS layout XOR-swizzled: 16B piece p of row r lives at piece slot (p ^ (r&7)).
__device__ __forceinline__ void gemm_mainloop(const bf16_t* __restrict__ Ablk,
                                              const bf16_t* __restrict__ Bblk,
                                              bf16_t* As, bf16_t* Bs,
                                              floatx4 acc[4][4], int wave, int lane) {
    int lr = lane & 15, lq = lane >> 4;
    int wr = (wave >> 1) * 64, wc = (wave & 1) * 64;
    for (int kt = 0; kt < C_DIM; kt += 64) {
#pragma unroll
        for (int j = 0; j < 4; ++j) {
            int chunk = j * 256 + wave * 64 + lane;       // 0..1023, wave-contiguous
            int r = chunk >> 3, ps = chunk & 7;
            int c = ((ps ^ (r & 7)) * 8);                 // swizzled source column
            load_lds16(Ablk + (size_t)r * C_DIM + kt + c, As + chunk * 8);
            load_lds16(Bblk + (size_t)r * C_DIM + kt + c, Bs + chunk * 8);
        }
        __syncthreads();
#pragma unroll
        for (int kk = 0; kk < 2; ++kk) {
            short8 af[4], bfr[4];
            int psw = ((kk * 4 + lq) ^ (lr & 7)) * 8;     // swizzled piece offset
#pragma unroll
            for (int m = 0; m < 4; ++m)
                af[m] = *reinterpret_cast<const short8*>(As + (wr + m * 16 + lr) * 64 + psw);
#pragma unroll
            for (int n = 0; n < 4; ++n)
                bfr[n] = *reinterpret_cast<const short8*>(Bs + (wc + n * 16 + lr) * 64 + psw);
#pragma unroll
            for (int m = 0; m < 4; ++m)
#pragma unroll
                for (int n = 0; n < 4; ++n)
                    acc[m][n] = mfma16(af[m], bfr[n], acc[m][n]);
        }
        __syncthreads();
    }
}

// ---------------------------------------------------------------- QKV GEMM
// grid (8, 64, 3). Block->tile mapping is XCD-swizzled: f = x + 8y + 512z,
// xcd = f&7 owns row-panels [8*xcd, 8*xcd+8). Within an XCD, the A-panel
// index cycles FASTEST -> A (2 MB) stays L2-resident, W panels stream once.
__global__ __launch_bounds__(256, 3) void gemm_qkv_kernel(
    const bf16_t* __restrict__ xb,
    const bf16_t* __restrict__ WqT, const bf16_t* __restrict__ WkT, const bf16_t* __restrict__ WvT,
    const float* __restrict__ bq, const float* __restrict__ bk, const float* __restrict__ bv,
    bf16_t* __restrict__ Q, bf16_t* __restrict__ K, bf16_t* __restrict__ Vt) {
    __shared__ bf16_t As[128 * 64];
    __shared__ bf16_t Bs[128 * 64];
    int tid = threadIdx.x, wave = tid >> 6, lane = tid & 63;

    int f    = (int)blockIdx.x + ((int)blockIdx.y << 3) + ((int)blockIdx.z << 9);
    int xcd  = f & 7;
    int s    = f >> 3;          // 0..191 per-XCD sequence
    int rloc = s & 7;           // A-panel: fastest
    int t2   = s >> 3;          // 0..23
    int colp = t2 & 7;          // W-panel
    int wsel = t2 >> 3;         // 0..2: z outermost per XCD
    int row0 = (xcd * 8 + rloc) * 128;
    int col0 = colp * 128;

    const bf16_t* Wt  = (wsel == 0) ? WqT : (wsel == 1) ? WkT : WvT;
    const float* bias = (wsel == 0) ? bq : (wsel == 1) ? bk : bv;

    floatx4 acc[4][4] = {};
    gemm_mainloop(xb + (size_t)row0 * C_DIM, Wt + (size_t)col0 * C_DIM, As, Bs, acc, wave, lane);

    int lr = lane & 15, lq = lane >> 4;
    int wr = (wave >> 1) * 64, wc = (wave & 1) * 64;

    if (wsel == 2) {
        // V transposed store, packed short4 (8B)
#pragma unroll
        for (int nt = 0; nt < 4; ++nt) {
            int col = col0 + wc + nt * 16 + lr;
            float bvv = bias[col];
            int h = col >> 6, d = col & 63;
#pragma unroll
            for (int m = 0; m < 4; ++m) {
                int rowg0 = row0 + wr + m * 16 + lq * 4;
                int b = rowg0 >> 11, t0 = rowg0 & (T_SEQ - 1);
                union { bf16_t h4[4]; short4 s4; } u;
#pragma unroll
                for (int r = 0; r < 4; ++r)
                    u.h4[r] = __float2bfloat16(acc[m][nt][r] + bvv);
                *reinterpret_cast<short4*>(
                    &Vt[((size_t)((b * NH + h) * HD + d)) * T_SEQ + t0]) = u.s4;
            }
        }
    } else {
        float scale = (wsel == 0) ? Q_SCALE : 1.0f;
        bf16_t* outp = (wsel == 0) ? Q : K;
#pragma unroll
        for (int nt = 0; nt < 4; ++nt) {
            int col = col0 + wc + nt * 16 + lr;
            float bvv = bias[col];
            int h = col >> 6, d = col & 63;
#pragma unroll
            for (int m = 0; m < 4; ++m) {
#pragma unroll
                for (int r = 0; r < 4; ++r) {
                    int rowg = row0 + wr + m * 16 + lq * 4 + r;
                    int b = rowg >> 11, t = rowg & (T_SEQ - 1);
                    float val = (acc[m][nt][r] + bvv) * scale;
                    outp[((size_t)((b * NH + h) * T_SEQ + t)) * HD + d] =
                        __float2bfloat16(val);
                }
            }
        }
    }
}

// ---------------------------------------------------------------- attention
// grid (8, 64), block 512 threads = 8 waves; each wave owns 16 q-rows.
// XCD-local heads: under round-robin dispatch xcd = blockIdx.x, and we map
// bh = 8*xcd + (y&7) so each XCD's K+V working set is 8 heads = 4 MB = its
// L2 (round-7 fix: FETCH was 147 MB with all-heads-per-XCD). qp = y>>3
// gives the uniform pass pair (15-qp, qp) = 34 iterations for every block.
// VALU diet: native v_exp_f32 via __builtin_amdgcn_exp2f (libm exp2f is a
// ~8-instr wrapper) and truncation-to-bf16 for the P store (RNE helper is
// ~6 instr; trunc of P in [0,1] is within bf16 noise).
__global__ __launch_bounds__(512, 4) void attn_kernel(
    const bf16_t* __restrict__ Q, const bf16_t* __restrict__ K,
    const bf16_t* __restrict__ Vt, bf16_t* __restrict__ ctx) {
    __shared__ __align__(16) bf16_t Ks[2][64 * 64];       // K tile  [k][d], swizzled
    __shared__ __align__(16) bf16_t Vs[2][64 * 64];       // Vt tile [d][k], swizzled
    __shared__ __align__(16) unsigned short Ps[128 * 64]; // P tile [q][k], swizzled
    int tid = threadIdx.x, w = tid >> 6, lane = tid & 63;
    int lr = lane & 15, lq = lane >> 4;
    int xcd = (int)blockIdx.x;
    int y   = (int)blockIdx.y;
    int bh  = xcd * 8 + (y & 7);      // XCD-local head group
    int qp  = y >> 3;                 // 0..7 pass pair
    int b = bh >> 4, h = bh & 15;

    const bf16_t* Kbase = K  + (size_t)bh * T_SEQ * HD;
    const bf16_t* Vbase = Vt + (size_t)bh * HD * T_SEQ;

#pragma unroll 1
    for (int pass = 0; pass < 2; ++pass) {
        int qt = pass ? qp : (15 - qp);
        int q0 = qt * 128;
        int ktiles = 2 * qt + 2;                      // always even
        const bf16_t* Qbase = Q + ((size_t)bh * T_SEQ + q0) * HD;

        // stage tile 0 into buffer 0 (512 threads: 1 chunk each for K and V).
        // Safe vs pass-0 stragglers: their last iteration reads buffer 1.
        {
            int ch = tid;
            int r = ch >> 3, ps = ch & 7;
            int c = ((ps ^ (r & 7)) * 8);
            load_lds16(Kbase + (size_t)r * HD + c, Ks[0] + ch * 8);
            load_lds16(Vbase + (size_t)r * T_SEQ + c, Vs[0] + ch * 8);
        }

        // Q fragments in registers: wave w owns rows [w*16, w*16+16)
        short8 qf[2];
#pragma unroll
        for (int kk = 0; kk < 2; ++kk)
            qf[kk] = *reinterpret_cast<const short8*>(
                Qbase + (size_t)(w * 16 + lr) * HD + kk * 32 + lq * 8);

        floatx4 o[4] = {};
        float lpart[4] = {};
        int buf = 0;

        for (int it = 0; it < ktiles; ++it) {
            int kt0 = it * 64;
            __syncthreads();   // drains stage(it) vmcnt; protects both buffers

            // prefetch next tile — drains at NEXT barrier (overlaps this compute)
            if (it + 1 < ktiles) {
                int nk0 = kt0 + 64;
                int ch = tid;
                int r = ch >> 3, ps = ch & 7;
                int c = ((ps ^ (r & 7)) * 8);
                load_lds16(Kbase + (size_t)(nk0 + r) * HD + c, Ks[buf ^ 1] + ch * 8);
                load_lds16(Vbase + (size_t)r * T_SEQ + nk0 + c, Vs[buf ^ 1] + ch * 8);
            }

            const bf16_t* Kc = Ks[buf];
            const bf16_t* Vc = Vs[buf];

            // S = Q K^T (log2 units)
            floatx4 s[4] = {};
            short8 kf[4][2];
#pragma unroll
            for (int kk = 0; kk < 2; ++kk) {
                int psw = ((kk * 4 + lq) ^ (lr & 7)) * 8;
#pragma unroll
                for (int n = 0; n < 4; ++n)
                    kf[n][kk] = *reinterpret_cast<const short8*>(Kc + (n * 16 + lr) * 64 + psw);
            }
#pragma unroll
            for (int kk = 0; kk < 2; ++kk)
#pragma unroll
                for (int n = 0; n < 4; ++n)
                    s[n] = mfma16(qf[kk], kf[n][kk], s[n]);

            // causal mask only on the last two tiles (block-uniform branch)
            if (it >= ktiles - 2) {
#pragma unroll
                for (int r = 0; r < 4; ++r) {
                    int rowg = q0 + w * 16 + lq * 4 + r;
#pragma unroll
                    for (int n = 0; n < 4; ++n) {
                        int colg = kt0 + n * 16 + lr;
                        if (colg > rowg) s[n][r] = -1e30f;
                    }
                }
            }

            // P = exp2(s): single v_exp_f32 each; per-lane l partials
#pragma unroll
            for (int n = 0; n < 4; ++n)
#pragma unroll
                for (int r = 0; r < 4; ++r)
                    s[n][r] = __builtin_amdgcn_exp2f(s[n][r]);
#pragma unroll
            for (int r = 0; r < 4; ++r)
                lpart[r] += (s[0][r] + s[1][r]) + (s[2][r] + s[3][r]);

            // dump P to LDS (C-layout -> A-layout; rows wave-private, trunc cvt)
#pragma unroll
            for (int n = 0; n < 4; ++n)
#pragma unroll
                for (int r = 0; r < 4; ++r) {
                    int prow = w * 16 + lq * 4 + r;
                    int piece = n * 2 + (lr >> 3);
                    union { float f; unsigned u; } cv; cv.f = s[n][r];
                    Ps[prow * 64 + ((piece ^ (prow & 7)) * 8) + (lr & 7)] =
                        (unsigned short)(cv.u >> 16);
                }

            // O += P V
            short8 pf[2], vf[4][2];
#pragma unroll
            for (int kk = 0; kk < 2; ++kk) {
                int prow = w * 16 + lr;
                pf[kk] = *reinterpret_cast<const short8*>(
                    Ps + prow * 64 + (((kk * 4 + lq) ^ (lr & 7)) * 8));
            }
#pragma unroll
            for (int kk = 0; kk < 2; ++kk) {
                int psw = ((kk * 4 + lq) ^ (lr & 7)) * 8;
#pragma unroll
                for (int dt = 0; dt < 4; ++dt)
                    vf[dt][kk] = *reinterpret_cast<const short8*>(Vc + (dt * 16 + lr) * 64 + psw);
            }
#pragma unroll
            for (int kk = 0; kk < 2; ++kk)
#pragma unroll
                for (int dt = 0; dt < 4; ++dt)
                    o[dt] = mfma16(pf[kk], vf[dt][kk], o[dt]);

            buf ^= 1;
        }

        // epilogue: reduce l across the 16 col-lanes (lane bits 0-3), normalize
#pragma unroll
        for (int r = 0; r < 4; ++r) {
            float l = lpart[r];
            l += __shfl_xor(l, 1);
            l += __shfl_xor(l, 2);
            l += __shfl_xor(l, 4);
            l += __shfl_xor(l, 8);
            float inv = 1.0f / l;
            int t = q0 + w * 16 + lq * 4 + r;
#pragma unroll
            for (int dt = 0; dt < 4; ++dt) {
                int d = dt * 16 + lr;
                ctx[((size_t)(b * T_SEQ + t)) * C_DIM + h * HD + d] =
                    __float2bfloat16(o[dt][r] * inv);
            }
        }
    }
}

// ---------------------------------------------------------------- output GEMM
// grid (8, 64), XCD-swizzled like gemm_qkv.
__global__ __launch_bounds__(256, 3) void gemm_out_kernel(
    const bf16_t* __restrict__ Actx, const bf16_t* __restrict__ WoT,
    const float* __restrict__ bo, float* __restrict__ out) {
    __shared__ bf16_t As[128 * 64];
    __shared__ bf16_t Bs[128 * 64];
    int tid = threadIdx.x, wave = tid >> 6, lane = tid & 63;

    int f    = (int)blockIdx.x + ((int)blockIdx.y << 3);
    int xcd  = f & 7;
    int s    = f >> 3;          // 0..63
    int rloc = s & 7;           // A-panel: fastest
    int colp = s >> 3;          // 0..7
    int row0 = (xcd * 8 + rloc) * 128;
    int col0 = colp * 128;

    floatx4 acc[4][4] = {};
    gemm_mainloop(Actx + (size_t)row0 * C_DIM, WoT + (size_t)col0 * C_DIM, As, Bs, acc, wave, lane);
    int lr = lane & 15, lq = lane >> 4;
    int wr = (wave >> 1) * 64, wc = (wave & 1) * 64;
#pragma unroll
    for (int nt = 0; nt < 4; ++nt) {
        int col = col0 + wc + nt * 16 + lr;
        float bvv = bo[col];
#pragma unroll
        for (int m = 0; m < 4; ++m)
#pragma unroll
            for (int r = 0; r < 4; ++r) {
                int rowg = row0 + wr + m * 16 + lq * 4 + r;
                out[(size_t)rowg * C_DIM + col] = acc[m][nt][r] + bvv;
            }
    }
}

// ---------------------------------------------------------------- launcher
extern "C" void kernel_launch(void* const* d_in, const int* in_sizes, int n_in,
                              void* d_out, int out_size, void* d_ws, size_t ws_size,
                              hipStream_t stream) {
    const float* x  = (const float*)d_in[0];
    const float* Wq = (const float*)d_in[1];
    const float* bq = (const float*)d_in[2];
    const float* Wk = (const float*)d_in[3];
    const float* bk = (const float*)d_in[4];
    const float* Wv = (const float*)d_in[5];
    const float* bv = (const float*)d_in[6];
    const float* Wo = (const float*)d_in[7];
    const float* bo = (const float*)d_in[8];
    float* out = (float*)d_out;

    char* ws = (char*)d_ws;
    bf16_t* xb  = (bf16_t*)ws; ws += (size_t)M_ROWS * C_DIM * 2;   // 16 MB
    bf16_t* WqT = (bf16_t*)ws; ws += (size_t)C_DIM * C_DIM * 2;    //  2 MB
    bf16_t* WkT = (bf16_t*)ws; ws += (size_t)C_DIM * C_DIM * 2;
    bf16_t* WvT = (bf16_t*)ws; ws += (size_t)C_DIM * C_DIM * 2;
    bf16_t* WoT = (bf16_t*)ws; ws += (size_t)C_DIM * C_DIM * 2;
    bf16_t* Qb  = (bf16_t*)ws; ws += (size_t)M_ROWS * C_DIM * 2;   // [B,H,T,D]
    bf16_t* Kb  = (bf16_t*)ws; ws += (size_t)M_ROWS * C_DIM * 2;   // [B,H,T,D]
    bf16_t* Vtb = (bf16_t*)ws; ws += (size_t)M_ROWS * C_DIM * 2;   // [B,H,D,T]
    bf16_t* ctx = (bf16_t*)ws; ws += (size_t)M_ROWS * C_DIM * 2;   // [B,T,C]

    convert_x_kernel<<<(M_ROWS * C_DIM / 4) / 256, 256, 0, stream>>>(x, xb);
    transpose_cvt_kernel<<<dim3(32, 32, 4), dim3(32, 8), 0, stream>>>(
        Wq, Wk, Wv, Wo, WqT, WkT, WvT, WoT);
    gemm_qkv_kernel<<<dim3(8, 64, 3), 256, 0, stream>>>(
        xb, WqT, WkT, WvT, bq, bk, bv, Qb, Kb, Vtb);
    attn_kernel<<<dim3(8, 64), 512, 0, stream>>>(Qb, Kb, Vtb, ctx);
    gemm_out_kernel<<<dim3(8, 64), 256, 0, stream>>>(ctx, WoT, bo, out);
}